// Round 7
// baseline (107.330 us; speedup 1.0000x reference)
//
#include <hip/hip_runtime.h>
#include <math.h>

#define NQ 12
#define NTH 256
#define NL 3
#define GRID 512   // R20: 2 blocks/CU x 256 CUs (measured residency); 8 pairs/block even

typedef _Float16 h8 __attribute__((ext_vector_type(8)));
typedef _Float16 h4 __attribute__((ext_vector_type(4)));
typedef float f4 __attribute__((ext_vector_type(4)));

#define MFMA __builtin_amdgcn_mfma_f32_16x16x32_f16

// R21 = R20 with the cvt_pkrtz type fix (builtin returns __fp16x2; capture
// with auto + memcpy). Changes vs R19 baseline:
//  (1) GRID 768->512: OccupancyPercent ~25% across R15-R19 says only
//      2 blocks/CU resident; 512 blocks x 8 pairs is an exact schedule.
//      Trig staging remapped: wlo/whi lanes 0-63, RX trig lanes 64-255.
//  (2) All f32->f16 convert+pack through v_cvt_pkrtz_f16_f32: 1 op per
//      packed pair vs ~3 (cvt+cvt+pack). ~Half the VALU budget was
//      conversions. RTZ rounding: absmax may rise (was 2^-9); revert pkrtz
//      alone if verify fails.
//
// Bit bookkeeping (state index i[11:0], wire w <-> bit 11-w):
//  L0 (LDS): off = i[11:4]*32 + reim*16 + i[3:0], swzf
//  g0 A: elem=i[2:0], q=(reim,i[3]), row u=(i[9:8],i[5:4]), mb=i[7:6], wave=i[11:10]
//  L1 (LDS): off = m1*32 + reim*16 + i[7:4], m1=(i[11:10],i[9:8],i[3:0]), swz1
//  g1 A: elem=i[6:4], q=(reim,i[7]), row=i[11:8], mb=i[1:0], wave=i[3:2]
//  in-reg transition -> g2 A: elem=i[10:8], q=(reim,i[11]), row=i[7:4], mb=i[1:0]
//  C(g2): col=i[11:8](lane3:0), l5:4=i[7:6], reg=i[5:4], mb=i[1:0], wave=i[3:2]
//  CNOT scatter: dest j = sfx(i) (suffix parity), h4-contiguous in j[1:0]<->mb.

__device__ __forceinline__ int sfx(int v) {
    v ^= v >> 1; v ^= v >> 2; v ^= v >> 4; v ^= v >> 8;
    return v;
}
__device__ __forceinline__ int swzf(int off) {   // L0 swizzle (R6-verified)
    return off ^ (((((off >> 6) ^ (off >> 9)) & 7)) << 3);
}
__device__ __forceinline__ int swz1(int off) {   // L1 swizzle (rank-3 bank classes both sides)
    return off ^ ((((off >> 5) ^ (off >> 9)) & 7) << 3);
}
__device__ __forceinline__ int swzw(int off) {   // W-buffer swizzle (R7-verified)
    return off ^ (((off >> 6) & 7) << 3);
}

// f32 pair -> packed 2xf16 dword via v_cvt_pkrtz_f16_f32 (lo in low half)
__device__ __forceinline__ unsigned pk2(float lo, float hi) {
    auto t_ = __builtin_amdgcn_cvt_pkrtz(lo, hi);   // __fp16x2
    unsigned r_; __builtin_memcpy(&r_, &t_, 4); return r_;
}

// C(g1) fragment (4 re regs + 4 im regs) -> A(g2) h8 fragment, in-wave.
__device__ __forceinline__ h8 xition(f4 re, f4 im) {
    unsigned a0 = pk2(re.x, re.y), a1 = pk2(re.z, re.w);
    unsigned b0 = pk2(im.x, im.y), b1 = pk2(im.z, im.w);
    asm("v_permlane32_swap_b32 %0, %1" : "+v"(a0), "+v"(b0));
    asm("v_permlane16_swap_b32 %0, %1" : "+v"(a0), "+v"(b0));
    asm("v_permlane32_swap_b32 %0, %1" : "+v"(a1), "+v"(b1));
    asm("v_permlane16_swap_b32 %0, %1" : "+v"(a1), "+v"(b1));
    union { unsigned u[4]; h8 v; } r_;
    r_.u[0] = a0; r_.u[1] = a1; r_.u[2] = b0; r_.u[3] = b1;
    return r_.v;
}

__global__ void __launch_bounds__(NTH, 3)
qsim_kernel(const float* __restrict__ x,
            const float* __restrict__ params,
            const float* __restrict__ head_w,
            const float* __restrict__ head_b,
            float* __restrict__ out, int Btot) {
    __shared__ __align__(16) _Float16 Sst[16384];  // 32 KB: states A | B(+8192)
    __shared__ __align__(16) _Float16 Wl[6144];    // 12 KB: layers 1..2 matrices
    __shared__ float wlo[64], whi[64];
    __shared__ float csx[8 * 24], snx[8 * 24];     // trig for up to 8 pairs
    __shared__ float Gs0[96];                      // layer-0 fused gates (persist)
    __shared__ __align__(16) float fct[2][48][2];  // per-pair factor tables A|B|C
    __shared__ float wred[8];
    float* Gs = (float*)Sst;   // 288-float overlay, dead after W-build

    const int t = threadIdx.x, blk = blockIdx.x;
    const int npairs = (Btot + 1) >> 1;

    // ---- Phase 1: lane ranges (gates t<36; wlo/whi t<64; trig t in [64,256)) ----
    if (t < 36) {   // fused 2x2 gates G = RY(p2)RZ(p1)RY(p0)  (R4-verified)
        float p0 = params[t * 3 + 0], p1 = params[t * 3 + 1], p2 = params[t * 3 + 2];
        float c0 = cosf(0.5f * p0), s0 = sinf(0.5f * p0);
        float ch = cosf(0.5f * p1), sh = sinf(0.5f * p1);
        float c2 = cosf(0.5f * p2), s2 = sinf(0.5f * p2);
        float pr_ = ch, pi = -sh, qr = ch, qi = sh;
        float A = c2 * c0, Bc = s2 * s0, Cc = c2 * s0, D = s2 * c0;
        float* g = &Gs[t * 8];
        g[0] = A * pr_ - Bc * qr;  g[1] = A * pi - Bc * qi;
        g[2] = -Cc * pr_ - D * qr; g[3] = -Cc * pi - D * qi;
        g[4] = D * pr_ + Cc * qr;  g[5] = D * pi + Cc * qi;
        g[6] = -Bc * pr_ + A * qr; g[7] = -Bc * pi + A * qi;
    }
    if (t < 64) {                  // wlo (bits<->wires 11..6) AND whi (wires 5..0)
        int v = t; float s = 0.f, s2 = 0.f;
#pragma unroll
        for (int be = 0; be < 6; ++be) {
            s  += ((v >> be) & 1) ? -head_w[11 - be] : head_w[11 - be];
            s2 += ((v >> be) & 1) ? -head_w[5 - be]  : head_w[5 - be];
        }
        wlo[v] = s; whi[v] = s2;
    }
    if (t >= 64) {                 // RX trig for this block's <=8 pairs
        int idx = t - 64;          // 0..191
        int pr = idx / 24, w = idx - pr * 24;
        int pairIdx = blk + pr * GRID;
        if (pairIdx < npairs) {
            int smp = pairIdx * 2 + (w >= 12 ? 1 : 0);
            int wire = (w >= 12) ? (w - 12) : w;
            if (smp < Btot) {
                float xv = 0.5f * x[smp * NQ + wire];
                csx[pr * 24 + w] = cosf(xv);
                snx[pr * 24 + w] = sinf(xv);
            }
        }
    }
    __syncthreads();

    // ---- Phase 2: W build for layers 1..2 + persist layer-0 gates ----
    if (t < 96) Gs0[t] = Gs[t];    // layer-0 gates, wires 0..11
#pragma unroll
    for (int i = 0; i < 24; ++i) {
        int e = i * 256 + t;       // 0..6143
        int s = (e >> 10) + 3;     // skip the 3 layer-0 matrices
        int idx = e & 1023;
        int n = idx >> 5, k = idx & 31;
        int rp = n >> 4, tp = n & 15, rr = k >> 4, tt = k & 15;
        int l = s / 3, g = s - 3 * l;
        float ur = 1.f, ui = 0.f;
#pragma unroll
        for (int jj = 0; jj < 4; ++jj) {
            int wire = 11 - (4 * g + jj);
            const float* gp = &Gs[(l * 12 + wire) * 8];
            int rb = (tp >> jj) & 1, cb = (tt >> jj) & 1;
            float gr = gp[(rb * 2 + cb) * 2], gi = gp[(rb * 2 + cb) * 2 + 1];
            float nr = ur * gr - ui * gi;
            float ni = ur * gi + ui * gr;
            ur = nr; ui = ni;
        }
        float val = (rp == 0) ? ((rr == 0) ? ur : -ui)
                              : ((rr == 0) ? ui : ur);
        Wl[swzw(e)] = (_Float16)val;
    }
    __syncthreads();

    // ---- per-lane constants ----
    const int wv = t >> 6, u = t & 15, q = (t >> 4) & 3;
    const int wbs = swzw(u * 32 + q * 8);
    int g0b[4], g1b[4];
#pragma unroll
    for (int mb = 0; mb < 4; ++mb) {
        int m_ = wv * 64 + (u >> 2) * 16 + mb * 4 + (u & 3);
        g0b[mb] = swzf(m_ * 32 + q * 8);
        int l_ = t & 63;
        int m1 = ((l_ >> 2) & 3) * 64 + (l_ & 3) * 16 + wv * 4 + mb;
        g1b[mb] = swz1(m1 * 32 + q * 8);
    }
    const int sb = (t * 32) ^ (((t ^ (t >> 4)) & 7) << 3);  // swz1(t*32)

    // CNOT-scatter (dest j = sfx(i)) + readout constants
    const int s4 = (u ^ (u >> 1) ^ (u >> 2) ^ (u >> 3)) & 15;
    const int P4 = s4 & 1, q0 = q & 1, q1 = q >> 1;
    const int j7 = q1 ^ P4, j6 = q0 ^ q1 ^ P4;
    const int wv0 = wv & 1, wv1 = wv >> 1;
    int Eo[4], PwR[4];
#pragma unroll
    for (int r = 0; r < 4; ++r) {
        int r0 = r & 1, r1 = r >> 1;
        int j5 = r1 ^ j6, j4 = (r0 ^ r1) ^ j6;
        int j3 = wv1 ^ j4, j2 = wv0 ^ wv1 ^ j4;
        int m0 = s4 * 16 + j7 * 8 + j6 * 4 + j5 * 2 + j4;
        Eo[r]  = swzf(m0 * 32 + j3 * 8 + j2 * 4);
        PwR[r] = (wv0 ^ wv1 ^ j4);
    }
    const int Pw0 = wv0 ^ wv1 ^ j6;
    const int wloB = j6 * 48 + (wv1 ^ j6) * 8 + (wv0 ^ wv1 ^ j6) * 4 + Pw0 * 3;
    const float whiv = whi[s4 * 4 + j7 * 2 + j6];
    const f4 Z = {0.f, 0.f, 0.f, 0.f};

    // layer-1 init constants: i = invsfx(j), j[11:4] = t
    const int iu = (t ^ (t >> 1)) & 0xFF;   // i[11:4]
    const int aI = iu >> 4;                 // A16 index i[11:8]
    const int bI = 16 + (iu & 15);          // B16 index i[7:4]
    const int flip = (t & 1) << 3;          // i3 = tau3 ^ j4

#define ST16(off_, va_, vb_) {                                               \
    union { unsigned u[4]; h8 v; } w_;                                       \
    w_.u[0] = pk2((va_).x, (va_).y); w_.u[1] = pk2((va_).z, (va_).w);        \
    w_.u[2] = pk2((vb_).x, (vb_).y); w_.u[3] = pk2((vb_).z, (vb_).w);        \
    *(h8*)&Sst[off_] = w_.v; }

// CNOT scatter of one reg-component r_ (both reims, both samples).
// slot order: Pw=0 -> (v0,v1,v3,v2); Pw=1 -> (v2,v3,v1,v0)
#define PST1(CMP_, r_) {                                                     \
    bool pw_ = PwR[r_] != 0;                                                 \
    { float v0=eRA[0].CMP_, v1=eRA[1].CMP_, v2=eRA[2].CMP_, v3=eRA[3].CMP_;  \
      float a0_=pw_?v2:v0, a1_=pw_?v3:v1, a2_=pw_?v1:v3, a3_=pw_?v0:v2;      \
      union { unsigned u[2]; h4 v; } w_;                                     \
      w_.u[0]=pk2(a0_,a1_); w_.u[1]=pk2(a2_,a3_);                            \
      *(h4*)&Sst[Eo[r_]] = w_.v; }                                           \
    { float v0=eIA[0].CMP_, v1=eIA[1].CMP_, v2=eIA[2].CMP_, v3=eIA[3].CMP_;  \
      float a0_=pw_?v2:v0, a1_=pw_?v3:v1, a2_=pw_?v1:v3, a3_=pw_?v0:v2;      \
      union { unsigned u[2]; h4 v; } w_;                                     \
      w_.u[0]=pk2(a0_,a1_); w_.u[1]=pk2(a2_,a3_);                            \
      *(h4*)&Sst[Eo[r_] ^ 16] = w_.v; }                                      \
    { float v0=eRB[0].CMP_, v1=eRB[1].CMP_, v2=eRB[2].CMP_, v3=eRB[3].CMP_;  \
      float a0_=pw_?v2:v0, a1_=pw_?v3:v1, a2_=pw_?v1:v3, a3_=pw_?v0:v2;      \
      union { unsigned u[2]; h4 v; } w_;                                     \
      w_.u[0]=pk2(a0_,a1_); w_.u[1]=pk2(a2_,a3_);                            \
      *(h4*)&Sst[Eo[r_] + 8192] = w_.v; }                                    \
    { float v0=eIB[0].CMP_, v1=eIB[1].CMP_, v2=eIB[2].CMP_, v3=eIB[3].CMP_;  \
      float a0_=pw_?v2:v0, a1_=pw_?v3:v1, a2_=pw_?v1:v3, a3_=pw_?v0:v2;      \
      union { unsigned u[2]; h4 v; } w_;                                     \
      w_.u[0]=pk2(a0_,a1_); w_.u[1]=pk2(a2_,a3_);                            \
      *(h4*)&Sst[(Eo[r_] ^ 16) + 8192] = w_.v; } }

#define RD1(CMP_, dr_) {                                                     \
    int b_ = wloB ^ (dr_);                                                   \
    float w0_ = whiv + wlo[b_],     w1_ = whiv + wlo[b_ ^ 1];                \
    float w2_ = whiv + wlo[b_ ^ 3], w3_ = whiv + wlo[b_ ^ 2];                \
    racc0 = fmaf(fmaf(eRA[0].CMP_, eRA[0].CMP_, eIA[0].CMP_*eIA[0].CMP_), w0_, racc0); \
    racc0 = fmaf(fmaf(eRA[1].CMP_, eRA[1].CMP_, eIA[1].CMP_*eIA[1].CMP_), w1_, racc0); \
    racc0 = fmaf(fmaf(eRA[2].CMP_, eRA[2].CMP_, eIA[2].CMP_*eIA[2].CMP_), w2_, racc0); \
    racc0 = fmaf(fmaf(eRA[3].CMP_, eRA[3].CMP_, eIA[3].CMP_*eIA[3].CMP_), w3_, racc0); \
    racc1 = fmaf(fmaf(eRB[0].CMP_, eRB[0].CMP_, eIB[0].CMP_*eIB[0].CMP_), w0_, racc1); \
    racc1 = fmaf(fmaf(eRB[1].CMP_, eRB[1].CMP_, eIB[1].CMP_*eIB[1].CMP_), w1_, racc1); \
    racc1 = fmaf(fmaf(eRB[2].CMP_, eRB[2].CMP_, eIB[2].CMP_*eIB[2].CMP_), w2_, racc1); \
    racc1 = fmaf(fmaf(eRB[3].CMP_, eRB[3].CMP_, eIB[3].CMP_*eIB[3].CMP_), w3_, racc1); }

    // ---- pair loop (grid-stride over 4096 pairs, 8 per block even) ----
#pragma unroll 1
    for (int pr = 0; ; ++pr) {
        const int pairIdx = blk + pr * GRID;
        if (pairIdx >= npairs) break;

        // ---- factor tables: fct[s][0..15]=A16, [16..31]=B16, [32..47]=C16 ----
        if (t < 96) {
            int s_ = t / 48, k_ = t - s_ * 48;
            int grp = k_ >> 4, h = k_ & 15;
            int wbase = (grp == 0) ? 3 : (grp == 1) ? 7 : 11;
            const float* cs_ = &csx[pr * 24 + s_ * 12];
            const float* sn_ = &snx[pr * 24 + s_ * 12];
            float ur = 1.f, ui = 0.f;
#pragma unroll
            for (int jj = 0; jj < 4; ++jj) {
                int w = wbase - jj;
                int bit = (h >> jj) & 1;
                const float* g = &Gs0[w * 8];
                float c = cs_[w], sn = sn_[w];
                float tr, ti;
                if (bit == 0) { tr = g[0] * c + g[3] * sn; ti = g[1] * c - g[2] * sn; }
                else          { tr = g[4] * c + g[7] * sn; ti = g[5] * c - g[6] * sn; }
                float nr = ur * tr - ui * ti, ni = ur * ti + ui * tr;
                ur = nr; ui = ni;
            }
            fct[s_][k_][0] = ur; fct[s_][k_][1] = ui;
        }
        __syncthreads();                              // (B1) tables ready

        // ---- materialize layer-1 input: state1[j] = A.B.C at i=invsfx(j) ----
        // (writes rows m=t: wave-local; no barrier needed before g0 reads)
#pragma unroll
        for (int s_ = 0; s_ < 2; ++s_) {
            const int SOFF = s_ * 8192;
            float ar = fct[s_][aI][0], ai = fct[s_][aI][1];
            float br = fct[s_][bI][0], bi = fct[s_][bI][1];
            float abr = ar * br - ai * bi, abi = ar * bi + ai * br;
            float cr[16], ci[16];
#pragma unroll
            for (int k = 0; k < 16; ++k) {            // flip folded into LDS addr
                cr[k] = fct[s_][32 + (k ^ flip)][0];
                ci[k] = fct[s_][32 + (k ^ flip)][1];
            }
            float vr_[16], vi_[16];
#pragma unroll
            for (int tau = 0; tau < 16; ++tau) {
                const int cidx = tau ^ (tau >> 1);    // compile-time
                vr_[tau] = abr * cr[cidx] - abi * ci[cidx];
                vi_[tau] = abr * ci[cidx] + abi * cr[cidx];
            }
            union { unsigned u[4]; h8 v; } R0_, R1_, I0_, I1_;
#pragma unroll
            for (int k = 0; k < 4; ++k) {
                R0_.u[k] = pk2(vr_[2 * k],     vr_[2 * k + 1]);
                R1_.u[k] = pk2(vr_[8 + 2 * k], vr_[8 + 2 * k + 1]);
                I0_.u[k] = pk2(vi_[2 * k],     vi_[2 * k + 1]);
                I1_.u[k] = pk2(vi_[8 + 2 * k], vi_[8 + 2 * k + 1]);
            }
            const int off0 = t * 32;
            *(h8*)&Sst[swzf(off0)      + SOFF] = R0_.v;
            *(h8*)&Sst[swzf(off0 + 8)  + SOFF] = R1_.v;
            *(h8*)&Sst[swzf(off0 + 16) + SOFF] = I0_.v;
            *(h8*)&Sst[swzf(off0 + 24) + SOFF] = I1_.v;
        }
        // (B2 elided: g0 reads below are wave-local to the rows just written)

        float racc0 = 0.f, racc1 = 0.f;
#pragma unroll
        for (int l = 1; l < NL; ++l) {
            // ---- g0: tau=i[3:0], then store to L1 (all wave-local; no (b)) ----
            {
                const int sW = ((l - 1) * 3 + 0) * 1024;
                h8 bf0 = *(const h8*)&Wl[sW + wbs];
                h8 bf1 = *(const h8*)&Wl[sW + 512 + wbs];
                h8 aA[4], aB[4];
#pragma unroll
                for (int mb = 0; mb < 4; ++mb) {
                    aA[mb] = *(const h8*)&Sst[g0b[mb]];
                    aB[mb] = *(const h8*)&Sst[g0b[mb] + 8192];
                }
                f4 cR[4], cI[4];
#pragma unroll
                for (int mb = 0; mb < 4; ++mb) {
                    cR[mb] = MFMA(aA[mb], bf0, Z, 0, 0, 0);
                    cI[mb] = MFMA(aA[mb], bf1, Z, 0, 0, 0);
                }
                ST16(sb,        cR[0], cR[1]) ST16(sb ^ 8,  cR[2], cR[3])
                ST16(sb ^ 16,   cI[0], cI[1]) ST16(sb ^ 24, cI[2], cI[3])
#pragma unroll
                for (int mb = 0; mb < 4; ++mb) {
                    cR[mb] = MFMA(aB[mb], bf0, Z, 0, 0, 0);
                    cI[mb] = MFMA(aB[mb], bf1, Z, 0, 0, 0);
                }
                ST16(sb + 8192,        cR[0], cR[1]) ST16((sb ^ 8) + 8192,  cR[2], cR[3])
                ST16((sb ^ 16) + 8192, cI[0], cI[1]) ST16((sb ^ 24) + 8192, cI[2], cI[3])
                __syncthreads();                      // (c) L1 ready
            }
            // ---- g1 (LDS read) -> in-reg transition -> g2 (register A) ----
            {
                const int sW1 = ((l - 1) * 3 + 1) * 1024, sW2 = ((l - 1) * 3 + 2) * 1024;
                h8 bg0 = *(const h8*)&Wl[sW1 + wbs];
                h8 bg1 = *(const h8*)&Wl[sW1 + 512 + wbs];
                h8 bh0 = *(const h8*)&Wl[sW2 + wbs];
                h8 bh1 = *(const h8*)&Wl[sW2 + 512 + wbs];
                h8 gA[4], gB[4];
#pragma unroll
                for (int mb = 0; mb < 4; ++mb) {
                    gA[mb] = *(const h8*)&Sst[g1b[mb]];
                    gB[mb] = *(const h8*)&Sst[g1b[mb] + 8192];
                }
                if (l < NL - 1) __syncthreads();      // (d) g1 reads done; scatter OK
                f4 eRA[4], eIA[4], eRB[4], eIB[4];
                {
                    f4 dR[4], dI[4]; h8 t2[4];
#pragma unroll
                    for (int mb = 0; mb < 4; ++mb) {
                        dR[mb] = MFMA(gA[mb], bg0, Z, 0, 0, 0);
                        dI[mb] = MFMA(gA[mb], bg1, Z, 0, 0, 0);
                    }
#pragma unroll
                    for (int mb = 0; mb < 4; ++mb) t2[mb] = xition(dR[mb], dI[mb]);
#pragma unroll
                    for (int mb = 0; mb < 4; ++mb) {
                        eRA[mb] = MFMA(t2[mb], bh0, Z, 0, 0, 0);
                        eIA[mb] = MFMA(t2[mb], bh1, Z, 0, 0, 0);
                    }
                }
                {
                    f4 dR[4], dI[4]; h8 t2[4];
#pragma unroll
                    for (int mb = 0; mb < 4; ++mb) {
                        dR[mb] = MFMA(gB[mb], bg0, Z, 0, 0, 0);
                        dI[mb] = MFMA(gB[mb], bg1, Z, 0, 0, 0);
                    }
#pragma unroll
                    for (int mb = 0; mb < 4; ++mb) t2[mb] = xition(dR[mb], dI[mb]);
#pragma unroll
                    for (int mb = 0; mb < 4; ++mb) {
                        eRB[mb] = MFMA(t2[mb], bh0, Z, 0, 0, 0);
                        eIB[mb] = MFMA(t2[mb], bh1, Z, 0, 0, 0);
                    }
                }
                if (l < NL - 1) {
                    PST1(x, 0) PST1(y, 1) PST1(z, 2) PST1(w, 3)
                    __syncthreads();                  // (e) L0' ready for next layer
                } else {
                    RD1(x, 0) RD1(y, 31) RD1(z, 63) RD1(w, 32)
                }
            }
        }
#pragma unroll
        for (int o = 32; o >= 1; o >>= 1) {
            racc0 += __shfl_xor(racc0, o, 64);
            racc1 += __shfl_xor(racc1, o, 64);
        }
        if ((t & 63) == 0) { wred[wv] = racc0; wred[4 + wv] = racc1; }
        __syncthreads();                              // wred + orders next iter
        if (t < 2) {
            int smp = pairIdx * 2 + t;
            if (smp < Btot) {
                float r = head_b[0];
#pragma unroll
                for (int i2 = 0; i2 < 4; ++i2) r += wred[t * 4 + i2];
                out[smp] = r;
            }
        }
    }
}

extern "C" void kernel_launch(void* const* d_in, const int* in_sizes, int n_in,
                              void* d_out, int out_size, void* d_ws, size_t ws_size,
                              hipStream_t stream) {
    const float* x = (const float*)d_in[0];
    const float* params = (const float*)d_in[1];
    const float* head_w = (const float*)d_in[2];
    const float* head_b = (const float*)d_in[3];
    float* out = (float*)d_out;
    int B = in_sizes[0] / NQ;

    hipLaunchKernelGGL(qsim_kernel, dim3(GRID), dim3(NTH), 0, stream,
                       x, params, head_w, head_b, out, B);
}

// Round 8
// 104.922 us; speedup vs baseline: 1.0230x; 1.0230x over previous
//
#include <hip/hip_runtime.h>
#include <math.h>

#define NQ 12
#define NTH 256
#define NL 3
#define GRID 1024  // R22: 1 sample/block, ~30.7 KB LDS -> 4-5 blocks/CU; 8 samples/block

typedef _Float16 h8 __attribute__((ext_vector_type(8)));
typedef _Float16 h4 __attribute__((ext_vector_type(4)));
typedef float f4 __attribute__((ext_vector_type(4)));

#define MFMA __builtin_amdgcn_mfma_f32_16x16x32_f16

// R22: single-sample blocks. R21 showed the kernel has ~10x issue slack
// (17.8k cy/pair vs <2k cy of issued work) -> latency/barrier bound at
// 2 blocks/CU (LDS 48.6 KB). Dropping the pair structure halves state LDS
// (Sst 32->16 KB, total ~30.7 KB) -> 4-5 resident blocks/CU = 2-2.5x
// occupancy. Per-sample barrier count doubles, but stalls now overlap
// across blocks. All index algebra unchanged; B-sample halves deleted.
// pkrtz kept (R21 passed, absmax 2^-8).
//
// Bit bookkeeping (state index i[11:0], wire w <-> bit 11-w):
//  L0 (LDS): off = i[11:4]*32 + reim*16 + i[3:0], swzf
//  g0 A: elem=i[2:0], q=(reim,i[3]), row u=(i[9:8],i[5:4]), mb=i[7:6], wave=i[11:10]
//  L1 (LDS): off = m1*32 + reim*16 + i[7:4], m1=(i[11:10],i[9:8],i[3:0]), swz1
//  g1 A: elem=i[6:4], q=(reim,i[7]), row=i[11:8], mb=i[1:0], wave=i[3:2]
//  in-reg transition -> g2 A: elem=i[10:8], q=(reim,i[11]), row=i[7:4], mb=i[1:0]
//  C(g2): col=i[11:8](lane3:0), l5:4=i[7:6], reg=i[5:4], mb=i[1:0], wave=i[3:2]
//  CNOT scatter: dest j = sfx(i) (suffix parity), h4-contiguous in j[1:0]<->mb.

__device__ __forceinline__ int sfx(int v) {
    v ^= v >> 1; v ^= v >> 2; v ^= v >> 4; v ^= v >> 8;
    return v;
}
__device__ __forceinline__ int swzf(int off) {   // L0 swizzle (R6-verified)
    return off ^ (((((off >> 6) ^ (off >> 9)) & 7)) << 3);
}
__device__ __forceinline__ int swz1(int off) {   // L1 swizzle (rank-3 bank classes both sides)
    return off ^ ((((off >> 5) ^ (off >> 9)) & 7) << 3);
}
__device__ __forceinline__ int swzw(int off) {   // W-buffer swizzle (R7-verified)
    return off ^ (((off >> 6) & 7) << 3);
}

// f32 pair -> packed 2xf16 dword via v_cvt_pkrtz_f16_f32 (lo in low half)
__device__ __forceinline__ unsigned pk2(float lo, float hi) {
    auto t_ = __builtin_amdgcn_cvt_pkrtz(lo, hi);   // __fp16x2
    unsigned r_; __builtin_memcpy(&r_, &t_, 4); return r_;
}

// C(g1) fragment (4 re regs + 4 im regs) -> A(g2) h8 fragment, in-wave.
__device__ __forceinline__ h8 xition(f4 re, f4 im) {
    unsigned a0 = pk2(re.x, re.y), a1 = pk2(re.z, re.w);
    unsigned b0 = pk2(im.x, im.y), b1 = pk2(im.z, im.w);
    asm("v_permlane32_swap_b32 %0, %1" : "+v"(a0), "+v"(b0));
    asm("v_permlane16_swap_b32 %0, %1" : "+v"(a0), "+v"(b0));
    asm("v_permlane32_swap_b32 %0, %1" : "+v"(a1), "+v"(b1));
    asm("v_permlane16_swap_b32 %0, %1" : "+v"(a1), "+v"(b1));
    union { unsigned u[4]; h8 v; } r_;
    r_.u[0] = a0; r_.u[1] = a1; r_.u[2] = b0; r_.u[3] = b1;
    return r_.v;
}

__global__ void __launch_bounds__(NTH, 4)
qsim_kernel(const float* __restrict__ x,
            const float* __restrict__ params,
            const float* __restrict__ head_w,
            const float* __restrict__ head_b,
            float* __restrict__ out, int Btot) {
    __shared__ __align__(16) _Float16 Sst[8192];   // 16 KB: one sample's state
    __shared__ __align__(16) _Float16 Wl[6144];    // 12 KB: layers 1..2 matrices
    __shared__ float wlo[64], whi[64];
    __shared__ float csx[8 * 12], snx[8 * 12];     // trig for up to 8 samples
    __shared__ float Gs0[96];                      // layer-0 fused gates (persist)
    __shared__ __align__(16) float fct[48][2];     // per-sample factor tables A|B|C
    __shared__ float wred[4];
    float* Gs = (float*)Sst;   // 288-float overlay, dead after W-build

    const int t = threadIdx.x, blk = blockIdx.x;

    // ---- Phase 1: lane ranges (gates t<36; wlo/whi t<64; trig t in [64,160)) ----
    if (t < 36) {   // fused 2x2 gates G = RY(p2)RZ(p1)RY(p0)  (R4-verified)
        float p0 = params[t * 3 + 0], p1 = params[t * 3 + 1], p2 = params[t * 3 + 2];
        float c0 = cosf(0.5f * p0), s0 = sinf(0.5f * p0);
        float ch = cosf(0.5f * p1), sh = sinf(0.5f * p1);
        float c2 = cosf(0.5f * p2), s2 = sinf(0.5f * p2);
        float pr_ = ch, pi = -sh, qr = ch, qi = sh;
        float A = c2 * c0, Bc = s2 * s0, Cc = c2 * s0, D = s2 * c0;
        float* g = &Gs[t * 8];
        g[0] = A * pr_ - Bc * qr;  g[1] = A * pi - Bc * qi;
        g[2] = -Cc * pr_ - D * qr; g[3] = -Cc * pi - D * qi;
        g[4] = D * pr_ + Cc * qr;  g[5] = D * pi + Cc * qi;
        g[6] = -Bc * pr_ + A * qr; g[7] = -Bc * pi + A * qi;
    }
    if (t < 64) {                  // wlo (bits<->wires 11..6) AND whi (wires 5..0)
        int v = t; float s = 0.f, s2 = 0.f;
#pragma unroll
        for (int be = 0; be < 6; ++be) {
            s  += ((v >> be) & 1) ? -head_w[11 - be] : head_w[11 - be];
            s2 += ((v >> be) & 1) ? -head_w[5 - be]  : head_w[5 - be];
        }
        wlo[v] = s; whi[v] = s2;
    }
    if (t >= 64 && t < 160) {      // RX trig for this block's <=8 samples
        int idx = t - 64;          // 0..95
        int pr = idx / 12, w = idx - pr * 12;
        int smp = blk + pr * GRID;
        if (smp < Btot) {
            float xv = 0.5f * x[smp * NQ + w];
            csx[pr * 12 + w] = cosf(xv);
            snx[pr * 12 + w] = sinf(xv);
        }
    }
    __syncthreads();

    // ---- Phase 2: W build for layers 1..2 + persist layer-0 gates ----
    if (t < 96) Gs0[t] = Gs[t];    // layer-0 gates, wires 0..11
#pragma unroll
    for (int i = 0; i < 24; ++i) {
        int e = i * 256 + t;       // 0..6143
        int s = (e >> 10) + 3;     // skip the 3 layer-0 matrices
        int idx = e & 1023;
        int n = idx >> 5, k = idx & 31;
        int rp = n >> 4, tp = n & 15, rr = k >> 4, tt = k & 15;
        int l = s / 3, g = s - 3 * l;
        float ur = 1.f, ui = 0.f;
#pragma unroll
        for (int jj = 0; jj < 4; ++jj) {
            int wire = 11 - (4 * g + jj);
            const float* gp = &Gs[(l * 12 + wire) * 8];
            int rb = (tp >> jj) & 1, cb = (tt >> jj) & 1;
            float gr = gp[(rb * 2 + cb) * 2], gi = gp[(rb * 2 + cb) * 2 + 1];
            float nr = ur * gr - ui * gi;
            float ni = ur * gi + ui * gr;
            ur = nr; ui = ni;
        }
        float val = (rp == 0) ? ((rr == 0) ? ur : -ui)
                              : ((rr == 0) ? ui : ur);
        Wl[swzw(e)] = (_Float16)val;
    }
    __syncthreads();

    // ---- per-lane constants ----
    const int wv = t >> 6, u = t & 15, q = (t >> 4) & 3;
    const int wbs = swzw(u * 32 + q * 8);
    int g0b[4], g1b[4];
#pragma unroll
    for (int mb = 0; mb < 4; ++mb) {
        int m_ = wv * 64 + (u >> 2) * 16 + mb * 4 + (u & 3);
        g0b[mb] = swzf(m_ * 32 + q * 8);
        int l_ = t & 63;
        int m1 = ((l_ >> 2) & 3) * 64 + (l_ & 3) * 16 + wv * 4 + mb;
        g1b[mb] = swz1(m1 * 32 + q * 8);
    }
    const int sb = (t * 32) ^ (((t ^ (t >> 4)) & 7) << 3);  // swz1(t*32)

    // CNOT-scatter (dest j = sfx(i)) + readout constants
    const int s4 = (u ^ (u >> 1) ^ (u >> 2) ^ (u >> 3)) & 15;
    const int P4 = s4 & 1, q0 = q & 1, q1 = q >> 1;
    const int j7 = q1 ^ P4, j6 = q0 ^ q1 ^ P4;
    const int wv0 = wv & 1, wv1 = wv >> 1;
    int Eo[4], PwR[4];
#pragma unroll
    for (int r = 0; r < 4; ++r) {
        int r0 = r & 1, r1 = r >> 1;
        int j5 = r1 ^ j6, j4 = (r0 ^ r1) ^ j6;
        int j3 = wv1 ^ j4, j2 = wv0 ^ wv1 ^ j4;
        int m0 = s4 * 16 + j7 * 8 + j6 * 4 + j5 * 2 + j4;
        Eo[r]  = swzf(m0 * 32 + j3 * 8 + j2 * 4);
        PwR[r] = (wv0 ^ wv1 ^ j4);
    }
    const int Pw0 = wv0 ^ wv1 ^ j6;
    const int wloB = j6 * 48 + (wv1 ^ j6) * 8 + (wv0 ^ wv1 ^ j6) * 4 + Pw0 * 3;
    const float whiv = whi[s4 * 4 + j7 * 2 + j6];
    const f4 Z = {0.f, 0.f, 0.f, 0.f};

    // layer-1 init constants: i = invsfx(j), j[11:4] = t
    const int iu = (t ^ (t >> 1)) & 0xFF;   // i[11:4]
    const int aI = iu >> 4;                 // A16 index i[11:8]
    const int bI = 16 + (iu & 15);          // B16 index i[7:4]
    const int flip = (t & 1) << 3;          // i3 = tau3 ^ j4

#define ST16(off_, va_, vb_) {                                               \
    union { unsigned u[4]; h8 v; } w_;                                       \
    w_.u[0] = pk2((va_).x, (va_).y); w_.u[1] = pk2((va_).z, (va_).w);        \
    w_.u[2] = pk2((vb_).x, (vb_).y); w_.u[3] = pk2((vb_).z, (vb_).w);        \
    *(h8*)&Sst[off_] = w_.v; }

// CNOT scatter of one reg-component r_ (both reims, one sample).
// slot order: Pw=0 -> (v0,v1,v3,v2); Pw=1 -> (v2,v3,v1,v0)
#define PST1(CMP_, r_) {                                                     \
    bool pw_ = PwR[r_] != 0;                                                 \
    { float v0=eRA[0].CMP_, v1=eRA[1].CMP_, v2=eRA[2].CMP_, v3=eRA[3].CMP_;  \
      float a0_=pw_?v2:v0, a1_=pw_?v3:v1, a2_=pw_?v1:v3, a3_=pw_?v0:v2;      \
      union { unsigned u[2]; h4 v; } w_;                                     \
      w_.u[0]=pk2(a0_,a1_); w_.u[1]=pk2(a2_,a3_);                            \
      *(h4*)&Sst[Eo[r_]] = w_.v; }                                           \
    { float v0=eIA[0].CMP_, v1=eIA[1].CMP_, v2=eIA[2].CMP_, v3=eIA[3].CMP_;  \
      float a0_=pw_?v2:v0, a1_=pw_?v3:v1, a2_=pw_?v1:v3, a3_=pw_?v0:v2;      \
      union { unsigned u[2]; h4 v; } w_;                                     \
      w_.u[0]=pk2(a0_,a1_); w_.u[1]=pk2(a2_,a3_);                            \
      *(h4*)&Sst[Eo[r_] ^ 16] = w_.v; } }

#define RD1(CMP_, dr_) {                                                     \
    int b_ = wloB ^ (dr_);                                                   \
    float w0_ = whiv + wlo[b_],     w1_ = whiv + wlo[b_ ^ 1];                \
    float w2_ = whiv + wlo[b_ ^ 3], w3_ = whiv + wlo[b_ ^ 2];                \
    racc0 = fmaf(fmaf(eRA[0].CMP_, eRA[0].CMP_, eIA[0].CMP_*eIA[0].CMP_), w0_, racc0); \
    racc0 = fmaf(fmaf(eRA[1].CMP_, eRA[1].CMP_, eIA[1].CMP_*eIA[1].CMP_), w1_, racc0); \
    racc0 = fmaf(fmaf(eRA[2].CMP_, eRA[2].CMP_, eIA[2].CMP_*eIA[2].CMP_), w2_, racc0); \
    racc0 = fmaf(fmaf(eRA[3].CMP_, eRA[3].CMP_, eIA[3].CMP_*eIA[3].CMP_), w3_, racc0); }

    // ---- sample loop (grid-stride over 8192 samples, 8 per block even) ----
#pragma unroll 1
    for (int pr = 0; ; ++pr) {
        const int smp = blk + pr * GRID;
        if (smp >= Btot) break;

        // ---- factor table: fct[0..15]=A16, [16..31]=B16, [32..47]=C16 ----
        if (t < 48) {
            int k_ = t;
            int grp = k_ >> 4, h = k_ & 15;
            int wbase = (grp == 0) ? 3 : (grp == 1) ? 7 : 11;
            const float* cs_ = &csx[pr * 12];
            const float* sn_ = &snx[pr * 12];
            float ur = 1.f, ui = 0.f;
#pragma unroll
            for (int jj = 0; jj < 4; ++jj) {
                int w = wbase - jj;
                int bit = (h >> jj) & 1;
                const float* g = &Gs0[w * 8];
                float c = cs_[w], sn = sn_[w];
                float tr, ti;
                if (bit == 0) { tr = g[0] * c + g[3] * sn; ti = g[1] * c - g[2] * sn; }
                else          { tr = g[4] * c + g[7] * sn; ti = g[5] * c - g[6] * sn; }
                float nr = ur * tr - ui * ti, ni = ur * ti + ui * tr;
                ur = nr; ui = ni;
            }
            fct[k_][0] = ur; fct[k_][1] = ui;
        }
        __syncthreads();                              // (B1) table ready

        // ---- materialize layer-1 input: state1[j] = A.B.C at i=invsfx(j) ----
        // (writes rows m=t: wave-local; no barrier needed before g0 reads)
        {
            float ar = fct[aI][0], ai = fct[aI][1];
            float br = fct[bI][0], bi = fct[bI][1];
            float abr = ar * br - ai * bi, abi = ar * bi + ai * br;
            float cr[16], ci[16];
#pragma unroll
            for (int k = 0; k < 16; ++k) {            // flip folded into LDS addr
                cr[k] = fct[32 + (k ^ flip)][0];
                ci[k] = fct[32 + (k ^ flip)][1];
            }
            float vr_[16], vi_[16];
#pragma unroll
            for (int tau = 0; tau < 16; ++tau) {
                const int cidx = tau ^ (tau >> 1);    // compile-time
                vr_[tau] = abr * cr[cidx] - abi * ci[cidx];
                vi_[tau] = abr * ci[cidx] + abi * cr[cidx];
            }
            union { unsigned u[4]; h8 v; } R0_, R1_, I0_, I1_;
#pragma unroll
            for (int k = 0; k < 4; ++k) {
                R0_.u[k] = pk2(vr_[2 * k],     vr_[2 * k + 1]);
                R1_.u[k] = pk2(vr_[8 + 2 * k], vr_[8 + 2 * k + 1]);
                I0_.u[k] = pk2(vi_[2 * k],     vi_[2 * k + 1]);
                I1_.u[k] = pk2(vi_[8 + 2 * k], vi_[8 + 2 * k + 1]);
            }
            const int off0 = t * 32;
            *(h8*)&Sst[swzf(off0)]      = R0_.v;
            *(h8*)&Sst[swzf(off0 + 8)]  = R1_.v;
            *(h8*)&Sst[swzf(off0 + 16)] = I0_.v;
            *(h8*)&Sst[swzf(off0 + 24)] = I1_.v;
        }
        // (B2 elided: g0 reads below are wave-local to the rows just written)

        float racc0 = 0.f;
#pragma unroll
        for (int l = 1; l < NL; ++l) {
            // ---- g0: tau=i[3:0], then store to L1 (all wave-local; no (b)) ----
            {
                const int sW = ((l - 1) * 3 + 0) * 1024;
                h8 bf0 = *(const h8*)&Wl[sW + wbs];
                h8 bf1 = *(const h8*)&Wl[sW + 512 + wbs];
                h8 aA[4];
#pragma unroll
                for (int mb = 0; mb < 4; ++mb)
                    aA[mb] = *(const h8*)&Sst[g0b[mb]];
                f4 cR[4], cI[4];
#pragma unroll
                for (int mb = 0; mb < 4; ++mb) {
                    cR[mb] = MFMA(aA[mb], bf0, Z, 0, 0, 0);
                    cI[mb] = MFMA(aA[mb], bf1, Z, 0, 0, 0);
                }
                ST16(sb,      cR[0], cR[1]) ST16(sb ^ 8,  cR[2], cR[3])
                ST16(sb ^ 16, cI[0], cI[1]) ST16(sb ^ 24, cI[2], cI[3])
                __syncthreads();                      // (c) L1 ready
            }
            // ---- g1 (LDS read) -> in-reg transition -> g2 (register A) ----
            {
                const int sW1 = ((l - 1) * 3 + 1) * 1024, sW2 = ((l - 1) * 3 + 2) * 1024;
                h8 bg0 = *(const h8*)&Wl[sW1 + wbs];
                h8 bg1 = *(const h8*)&Wl[sW1 + 512 + wbs];
                h8 bh0 = *(const h8*)&Wl[sW2 + wbs];
                h8 bh1 = *(const h8*)&Wl[sW2 + 512 + wbs];
                h8 gA[4];
#pragma unroll
                for (int mb = 0; mb < 4; ++mb)
                    gA[mb] = *(const h8*)&Sst[g1b[mb]];
                if (l < NL - 1) __syncthreads();      // (d) g1 reads done; scatter OK
                f4 eRA[4], eIA[4];
                {
                    f4 dR[4], dI[4]; h8 t2[4];
#pragma unroll
                    for (int mb = 0; mb < 4; ++mb) {
                        dR[mb] = MFMA(gA[mb], bg0, Z, 0, 0, 0);
                        dI[mb] = MFMA(gA[mb], bg1, Z, 0, 0, 0);
                    }
#pragma unroll
                    for (int mb = 0; mb < 4; ++mb) t2[mb] = xition(dR[mb], dI[mb]);
#pragma unroll
                    for (int mb = 0; mb < 4; ++mb) {
                        eRA[mb] = MFMA(t2[mb], bh0, Z, 0, 0, 0);
                        eIA[mb] = MFMA(t2[mb], bh1, Z, 0, 0, 0);
                    }
                }
                if (l < NL - 1) {
                    PST1(x, 0) PST1(y, 1) PST1(z, 2) PST1(w, 3)
                    __syncthreads();                  // (e) L0' ready for next layer
                } else {
                    RD1(x, 0) RD1(y, 31) RD1(z, 63) RD1(w, 32)
                }
            }
        }
#pragma unroll
        for (int o = 32; o >= 1; o >>= 1)
            racc0 += __shfl_xor(racc0, o, 64);
        if ((t & 63) == 0) wred[wv] = racc0;
        __syncthreads();                              // wred + orders next iter
        if (t == 0) {
            float r = head_b[0];
#pragma unroll
            for (int i2 = 0; i2 < 4; ++i2) r += wred[i2];
            out[smp] = r;
        }
    }
}

extern "C" void kernel_launch(void* const* d_in, const int* in_sizes, int n_in,
                              void* d_out, int out_size, void* d_ws, size_t ws_size,
                              hipStream_t stream) {
    const float* x = (const float*)d_in[0];
    const float* params = (const float*)d_in[1];
    const float* head_w = (const float*)d_in[2];
    const float* head_b = (const float*)d_in[3];
    float* out = (float*)d_out;
    int B = in_sizes[0] / NQ;

    hipLaunchKernelGGL(qsim_kernel, dim3(GRID), dim3(NTH), 0, stream,
                       x, params, head_w, head_b, out, B);
}